// Round 3
// baseline (246.657 us; speedup 1.0000x reference)
//
#include <hip/hip_runtime.h>
#include <math.h>

#define DIM 4096
#define HD 128
#define NH 32
#define NKV 8
#define CACHE_LEN 8192
#define NCHUNK 128        // chunks per kv head
#define CHUNK 64          // positions per chunk
#define SCALE 0.08838834764831845f  // 1/sqrt(128)

// ---------------- K0: RoPE cos/sin table (f64 math, one wave) ----------------
// Must match numpy f32 semantics: te = fl32(500000^(p/64)); invf = fl32(1/te);
// freq = fl32(sidx*invf); c,s = fl32(cos/sin(double(freq))).
// f64 transcendentals are slow software routines -> isolate them here instead
// of paying the tail in every qkv block.
__global__ __launch_bounds__(64) void rope_table_kernel(
    const int* __restrict__ start_idx_p, float* __restrict__ tab /* [2][64] */)
{
    const int p = threadIdx.x;   // 0..63
    const float te   = (float)pow(500000.0, (double)p * (1.0/64.0));
    const float invf = 1.0f / te;
    const float freq = (float)(*start_idx_p) * invf;
    const double ang = (double)freq;
    tab[p]      = (float)cos(ang);
    tab[64 + p] = (float)sin(ang);
}

// ---------------- K1: QKV GEMV + RoPE + cache update ----------------
// One block (256 thr) per ROW PAIR (2i, 2i+1): waves 0,1 -> even row halves,
// waves 2,3 -> odd row halves. grid = 3072.
__global__ __launch_bounds__(256) void qkv_rope_kernel(
    const float* __restrict__ x, const float* __restrict__ wq,
    const float* __restrict__ wk, const float* __restrict__ wv,
    float* __restrict__ k_cache, float* __restrict__ v_cache,
    const int* __restrict__ start_idx_p, const float* __restrict__ tab,
    float* __restrict__ q_out)
{
    const int wave = threadIdx.x >> 6;
    const int lane = threadIdx.x & 63;
    const int r0   = blockIdx.x * 2;            // even row of the pair
    const int rrow = r0 + (wave >> 1);          // this wave's row
    const int sub  = wave & 1;                  // which half of the row

    const float* w;
    if (rrow < DIM)                w = wq + (size_t)rrow * DIM;
    else if (rrow < DIM + NKV*HD)  w = wk + (size_t)(rrow - DIM) * DIM;
    else                           w = wv + (size_t)(rrow - DIM - NKV*HD) * DIM;

    const float4* w4 = (const float4*)w + sub*512;
    const float4* x4 = (const float4*)x + sub*512;
    float acc = 0.f;
#pragma unroll
    for (int it = 0; it < 8; ++it) {
        float4 a = w4[it*64 + lane];
        float4 b = x4[it*64 + lane];
        acc = fmaf(a.x, b.x, acc); acc = fmaf(a.y, b.y, acc);
        acc = fmaf(a.z, b.z, acc); acc = fmaf(a.w, b.w, acc);
    }
#pragma unroll
    for (int off = 32; off > 0; off >>= 1) acc += __shfl_down(acc, off);

    __shared__ float dots[4];
    if (lane == 0) dots[wave] = acc;
    __syncthreads();

    if (threadIdx.x == 0) {
        const float de = dots[0] + dots[1];     // even-row dot
        const float dd = dots[2] + dots[3];     // odd-row dot
        const int sidx = *start_idx_p;
        if (r0 < DIM + NKV*HD) {
            const int local = (r0 < DIM) ? r0 : r0 - DIM;
            const int p = (local & (HD-1)) >> 1;   // pair index 0..63
            const float c = tab[p], s = tab[64 + p];
            const float re = de * c - dd * s;
            const float ro = de * s + dd * c;
            if (r0 < DIM) {
                q_out[r0] = re; q_out[r0+1] = ro;
            } else {
                const size_t base = (size_t)sidx * (NKV*HD) + (size_t)(r0 - DIM);
                k_cache[base] = re; k_cache[base+1] = ro;
            }
        } else {
            const size_t base = (size_t)sidx * (NKV*HD) + (size_t)(r0 - DIM - NKV*HD);
            v_cache[base] = de; v_cache[base+1] = dd;
        }
    }
}

// ---------------- K2: flash-decode partials ----------------
// Grid: 8 kv-heads x 128 chunks of 64 positions. Block = 256 = 4 waves x 4
// 16-lane groups; each group owns 4 positions, processed 2 at a time with all
// 8 K/V float4 loads issued before the reduce (pipelined).
__global__ __launch_bounds__(256) void attn_partial_kernel(
    const float* __restrict__ q, const float* __restrict__ k_cache,
    const float* __restrict__ v_cache,
    float* __restrict__ part_acc,   // [1024][4*HD]
    float* __restrict__ part_l)     // [1024][4]
{
    const int kv    = blockIdx.x >> 7;
    const int chunk = blockIdx.x & (NCHUNK-1);
    const int wave  = threadIdx.x >> 6;
    const int lane  = threadIdx.x & 63;
    const int g  = lane >> 4;   // group 0..3
    const int gl = lane & 15;   // lane in group; owns d = gl*4 and 64+gl*4

    float4 q0[4], q1[4];
#pragma unroll
    for (int hh = 0; hh < 4; ++hh) {
        const float* qb = q + (size_t)(kv*4 + hh) * HD;
        float4 a = *(const float4*)(qb + gl*4);
        float4 b = *(const float4*)(qb + 64 + gl*4);
        a.x *= SCALE; a.y *= SCALE; a.z *= SCALE; a.w *= SCALE;
        b.x *= SCALE; b.y *= SCALE; b.z *= SCALE; b.w *= SCALE;
        q0[hh] = a; q1[hh] = b;
    }

    float acc0[4][4] = {{0}}, acc1[4][4] = {{0}};
    float lsum[4] = {0.f, 0.f, 0.f, 0.f};

    const int pbase = chunk*CHUNK + wave*16 + g*4;
#pragma unroll
    for (int it = 0; it < 4; it += 2) {
        const int posA = pbase + it, posB = pbase + it + 1;
        const float* kA = k_cache + ((size_t)posA*NKV + kv) * HD;
        const float* kB = k_cache + ((size_t)posB*NKV + kv) * HD;
        const float* vA = v_cache + ((size_t)posA*NKV + kv) * HD;
        const float* vB = v_cache + ((size_t)posB*NKV + kv) * HD;
        float4 k0A = *(const float4*)(kA + gl*4);
        float4 k1A = *(const float4*)(kA + 64 + gl*4);
        float4 k0B = *(const float4*)(kB + gl*4);
        float4 k1B = *(const float4*)(kB + 64 + gl*4);
        float4 v0A = *(const float4*)(vA + gl*4);
        float4 v1A = *(const float4*)(vA + 64 + gl*4);
        float4 v0B = *(const float4*)(vB + gl*4);
        float4 v1B = *(const float4*)(vB + 64 + gl*4);

        float sA[4], sB[4];
#pragma unroll
        for (int hh = 0; hh < 4; ++hh) {
            float t;
            t  = q0[hh].x*k0A.x + q0[hh].y*k0A.y + q0[hh].z*k0A.z + q0[hh].w*k0A.w;
            t += q1[hh].x*k1A.x + q1[hh].y*k1A.y + q1[hh].z*k1A.z + q1[hh].w*k1A.w;
            sA[hh] = t;
            t  = q0[hh].x*k0B.x + q0[hh].y*k0B.y + q0[hh].z*k0B.z + q0[hh].w*k0B.w;
            t += q1[hh].x*k1B.x + q1[hh].y*k1B.y + q1[hh].z*k1B.z + q1[hh].w*k1B.w;
            sB[hh] = t;
        }
#pragma unroll
        for (int off = 1; off < 16; off <<= 1) {
#pragma unroll
            for (int hh = 0; hh < 4; ++hh) {
                sA[hh] += __shfl_xor(sA[hh], off);
                sB[hh] += __shfl_xor(sB[hh], off);
            }
        }
#pragma unroll
        for (int hh = 0; hh < 4; ++hh) {
            const float pA = expf(sA[hh]);
            const float pB = expf(sB[hh]);
            lsum[hh] += pA + pB;
            acc0[hh][0] = fmaf(pA, v0A.x, fmaf(pB, v0B.x, acc0[hh][0]));
            acc0[hh][1] = fmaf(pA, v0A.y, fmaf(pB, v0B.y, acc0[hh][1]));
            acc0[hh][2] = fmaf(pA, v0A.z, fmaf(pB, v0B.z, acc0[hh][2]));
            acc0[hh][3] = fmaf(pA, v0A.w, fmaf(pB, v0B.w, acc0[hh][3]));
            acc1[hh][0] = fmaf(pA, v1A.x, fmaf(pB, v1B.x, acc1[hh][0]));
            acc1[hh][1] = fmaf(pA, v1A.y, fmaf(pB, v1B.y, acc1[hh][1]));
            acc1[hh][2] = fmaf(pA, v1A.z, fmaf(pB, v1B.z, acc1[hh][2]));
            acc1[hh][3] = fmaf(pA, v1A.w, fmaf(pB, v1B.w, acc1[hh][3]));
        }
    }

    // cross-group reduce (groups hold disjoint positions, same dims)
#pragma unroll
    for (int off = 16; off < 64; off <<= 1) {
#pragma unroll
        for (int hh = 0; hh < 4; ++hh) {
            lsum[hh] += __shfl_xor(lsum[hh], off);
#pragma unroll
            for (int j = 0; j < 4; ++j) {
                acc0[hh][j] += __shfl_xor(acc0[hh][j], off);
                acc1[hh][j] += __shfl_xor(acc1[hh][j], off);
            }
        }
    }

    // cross-wave reduce via LDS
    __shared__ float red[4][4*HD];
    __shared__ float lred[4][4];
    if (lane < 16) {
#pragma unroll
        for (int hh = 0; hh < 4; ++hh) {
            *(float4*)&red[wave][hh*HD + gl*4] =
                make_float4(acc0[hh][0], acc0[hh][1], acc0[hh][2], acc0[hh][3]);
            *(float4*)&red[wave][hh*HD + 64 + gl*4] =
                make_float4(acc1[hh][0], acc1[hh][1], acc1[hh][2], acc1[hh][3]);
        }
        if (gl == 0) {
            lred[wave][0] = lsum[0]; lred[wave][1] = lsum[1];
            lred[wave][2] = lsum[2]; lred[wave][3] = lsum[3];
        }
    }
    __syncthreads();

    float* outp = part_acc + (size_t)blockIdx.x * (4*HD);
#pragma unroll
    for (int k = 0; k < 2; ++k) {
        const int idx = (int)threadIdx.x + k*256;
        outp[idx] = red[0][idx] + red[1][idx] + red[2][idx] + red[3][idx];
    }
    if (threadIdx.x < 4) {
        part_l[(size_t)blockIdx.x*4 + threadIdx.x] =
            lred[0][threadIdx.x] + lred[1][threadIdx.x] +
            lred[2][threadIdx.x] + lred[3][threadIdx.x];
    }
}

// ---------------- K3: combine partials ----------------
__global__ __launch_bounds__(128) void attn_combine_kernel(
    const float* __restrict__ part_acc, const float* __restrict__ part_l,
    float* __restrict__ attn_out)
{
    const int h  = blockIdx.x;      // 0..31
    const int kv = h >> 2, hh = h & 3;
    const int d  = threadIdx.x;     // 0..127
    float acc = 0.f, l = 0.f;
    for (int c = 0; c < NCHUNK; ++c) {
        const int pid = kv*NCHUNK + c;
        acc += part_acc[(size_t)pid*(4*HD) + hh*HD + d];
        l   += part_l[pid*4 + hh];
    }
    attn_out[h*HD + d] = acc / l;
}

// ---------------- K4: output projection GEMV ----------------
// One block (256 thr, 4 waves) per output row; grid 4096.
__global__ __launch_bounds__(256) void out_proj_kernel(
    const float* __restrict__ attn, const float* __restrict__ wo,
    float* __restrict__ out)
{
    const int row = blockIdx.x;
    const float4* w4 = (const float4*)(wo + (size_t)row * DIM);
    const float4* a4 = (const float4*)attn;
    float acc = 0.f;
#pragma unroll
    for (int it = 0; it < 4; ++it) {
        float4 a = w4[it*256 + threadIdx.x];
        float4 b = a4[it*256 + threadIdx.x];
        acc = fmaf(a.x, b.x, acc); acc = fmaf(a.y, b.y, acc);
        acc = fmaf(a.z, b.z, acc); acc = fmaf(a.w, b.w, acc);
    }
#pragma unroll
    for (int off = 32; off > 0; off >>= 1) acc += __shfl_down(acc, off);
    __shared__ float dots[4];
    if ((threadIdx.x & 63) == 0) dots[threadIdx.x >> 6] = acc;
    __syncthreads();
    if (threadIdx.x == 0) out[row] = dots[0] + dots[1] + dots[2] + dots[3];
}

extern "C" void kernel_launch(void* const* d_in, const int* in_sizes, int n_in,
                              void* d_out, int out_size, void* d_ws, size_t ws_size,
                              hipStream_t stream)
{
    const float* x  = (const float*)d_in[0];
    const float* wq = (const float*)d_in[1];
    const float* wk = (const float*)d_in[2];
    const float* wv = (const float*)d_in[3];
    const float* wo = (const float*)d_in[4];
    float* k_cache  = (float*)d_in[5];   // written at [start_idx]; harness restores inputs every launch
    float* v_cache  = (float*)d_in[6];
    const int* sidx = (const int*)d_in[7];
    float* out = (float*)d_out;

    float* ws       = (float*)d_ws;
    float* q        = ws;                          // 4096
    float* part_acc = ws + 4096;                   // 1024 * 512
    float* part_l   = part_acc + 1024*512;         // 4096
    float* attn     = part_l + 4096;               // 4096
    float* tab      = attn + 4096;                 // 128

    hipLaunchKernelGGL(rope_table_kernel, dim3(1), dim3(64), 0, stream, sidx, tab);
    hipLaunchKernelGGL(qkv_rope_kernel, dim3((DIM + NKV*HD*2)/2), dim3(256), 0, stream,
                       x, wq, wk, wv, k_cache, v_cache, sidx, tab, q);
    hipLaunchKernelGGL(attn_partial_kernel, dim3(NKV*NCHUNK), dim3(256), 0, stream,
                       q, k_cache, v_cache, part_acc, part_l);
    hipLaunchKernelGGL(attn_combine_kernel, dim3(NH), dim3(HD), 0, stream,
                       part_acc, part_l, attn);
    hipLaunchKernelGGL(out_proj_kernel, dim3(DIM), dim3(256), 0, stream,
                       attn, wo, out);
}